// Round 1
// baseline (686.608 us; speedup 1.0000x reference)
//
#include <hip/hip_runtime.h>
#include <cstdint>

typedef unsigned long long u64;
typedef unsigned int u32;

#define WPRE 400          // PRE_NMS
#define MIN_SCORE 0.01f
#define MAX_OVERLAP 0.45f

// ---- sortable key packing: (score desc, index asc) <=> key desc; keys unique ----
__device__ __forceinline__ u64 score_key(float f, int idx) {
    u32 u = __float_as_uint(f);
    u32 k32 = (f >= 0.0f) ? (u | 0x80000000u) : ~u;
    return ((u64)k32 << 32) | (u64)(0xFFFFFFFFu - (u32)idx);
}
__device__ __forceinline__ float key_score(u64 k) {
    u32 k32 = (u32)(k >> 32);
    u32 u = (k32 & 0x80000000u) ? (k32 ^ 0x80000000u) : ~k32;
    return __uint_as_float(u);
}
__device__ __forceinline__ int key_idx(u64 k) {
    return (int)(0xFFFFFFFFu - (u32)(k & 0xFFFFFFFFu));
}

// ---------------- Kernel 1: decode boxes + softmax (class-transposed) ----------------
__global__ __launch_bounds__(256) void decode_softmax_kernel(
    const float* __restrict__ locs, const float* __restrict__ scores,
    const float* __restrict__ priors, float* __restrict__ dec,
    float* __restrict__ probs_t, int P, int C, int NC)
{
    int p = blockIdx.x * 256 + threadIdx.x;
    int b = blockIdx.y;
    if (p >= P) return;

    float pcx = priors[p*4+0], pcy = priors[p*4+1];
    float pw  = priors[p*4+2], ph  = priors[p*4+3];
    const float* lc = locs + ((size_t)b*P + p)*4;
    float cx = lc[0] * pw / 10.0f + pcx;
    float cy = lc[1] * ph / 10.0f + pcy;
    float w  = expf(lc[2] / 5.0f) * pw;
    float h  = expf(lc[3] / 5.0f) * ph;
    float* d = dec + ((size_t)b*P + p)*4;
    d[0] = cx - w*0.5f; d[1] = cy - h*0.5f;
    d[2] = cx + w*0.5f; d[3] = cy + h*0.5f;

    const float* sc = scores + ((size_t)b*P + p)*C;
    float m = sc[0];
    for (int c = 1; c < C; ++c) m = fmaxf(m, sc[c]);
    float ssum = 0.f;
    for (int c = 0; c < C; ++c) ssum += expf(sc[c] - m);
    for (int c = 1; c < C; ++c)
        probs_t[((size_t)(b*NC + (c-1)))*P + p] = expf(sc[c] - m) / ssum;
}

// ---------------- Kernel 2: per (class,image) top-400 + NMS ----------------
__global__ __launch_bounds__(256) void nms_kernel(
    const float* __restrict__ dec, const float* __restrict__ probs_t,
    float* __restrict__ cand_sc, float* __restrict__ cand_bx,
    int P, int NC)
{
    const int c = blockIdx.x, b = blockIdx.y;
    const int tid = threadIdx.x;
    const float* ps = probs_t + ((size_t)(b*NC + c))*P;

    __shared__ u32 hist[256];
    __shared__ u64 cand[512];
    __shared__ float cbox[WPRE][4];
    __shared__ float area[WPRE];
    __shared__ float vals[WPRE];
    __shared__ unsigned char validf[WPRE];
    __shared__ unsigned char sup[WPRE];
    __shared__ u64 sh_prefix;
    __shared__ int sh_r, sh_cnt;

    if (tid == 0) { sh_prefix = 0ull; sh_r = WPRE; sh_cnt = 0; }
    __syncthreads();

    // MSD radix-select: exact WPRE-th largest key (keys unique)
    for (int d = 7; d >= 0; --d) {
        hist[tid] = 0;
        __syncthreads();
        u64 pref = sh_prefix;
        for (int i = tid; i < P; i += 256) {
            float f = ps[i];
            f = (f > MIN_SCORE) ? f : -1.0f;
            u64 k = score_key(f, i);
            bool match = (d == 7) || ((k >> ((d+1)*8)) == pref);
            if (match) atomicAdd(&hist[(u32)(k >> (d*8)) & 255u], 1u);
        }
        __syncthreads();
        if (tid == 0) {
            u32 r = (u32)sh_r, cum = 0; int sel = 0;
            for (int v = 255; v >= 0; --v) {
                u32 h = hist[v];
                if (cum + h >= r) { sel = v; sh_r = (int)(r - cum); break; }
                cum += h;
            }
            sh_prefix = (pref << 8) | (u64)(u32)sel;
        }
        __syncthreads();
    }
    u64 pivot = sh_prefix;

    // compact the exactly-WPRE keys >= pivot
    for (int i = tid; i < P; i += 256) {
        float f = ps[i];
        f = (f > MIN_SCORE) ? f : -1.0f;
        u64 k = score_key(f, i);
        if (k >= pivot) {
            int pos = atomicAdd(&sh_cnt, 1);
            if (pos < WPRE) cand[pos] = k;
        }
    }
    for (int i = WPRE + tid; i < 512; i += 256) cand[i] = 0ull;
    __syncthreads();

    // bitonic sort 512 descending
    for (int k = 2; k <= 512; k <<= 1) {
        for (int j = k >> 1; j > 0; j >>= 1) {
            for (int t = tid; t < 512; t += 256) {
                int ixj = t ^ j;
                if (ixj > t) {
                    u64 a = cand[t], bb = cand[ixj];
                    if (((t & k) == 0) ? (a < bb) : (a > bb)) {
                        cand[t] = bb; cand[ixj] = a;
                    }
                }
            }
            __syncthreads();
        }
    }

    // unpack, gather boxes, init NMS state
    for (int i = tid; i < WPRE; i += 256) {
        u64 k = cand[i];
        float v = key_score(k);
        vals[i] = v;
        validf[i] = (v > MIN_SCORE) ? 1 : 0;
        int p = key_idx(k);
        const float* bx = dec + ((size_t)b*P + p)*4;
        float x0 = bx[0], y0 = bx[1], x1 = bx[2], y1 = bx[3];
        cbox[i][0] = x0; cbox[i][1] = y0; cbox[i][2] = x1; cbox[i][3] = y1;
        area[i] = (x1 - x0) * (y1 - y0);
        sup[i] = 0;
    }
    __syncthreads();

    // sequential NMS scan (exact reference semantics)
    for (int i = 0; i < WPRE; ++i) {
        bool active = validf[i] && !sup[i];   // uniform LDS broadcast read
        __syncthreads();                      // everyone read sup[i] before writes
        if (active) {
            float ax0 = cbox[i][0], ay0 = cbox[i][1];
            float ax1 = cbox[i][2], ay1 = cbox[i][3];
            float aarea = area[i];
            for (int j = tid; j < WPRE; j += 256) {
                float lx = fmaxf(ax0, cbox[j][0]);
                float ly = fmaxf(ay0, cbox[j][1]);
                float rx = fminf(ax1, cbox[j][2]);
                float ry = fminf(ay1, cbox[j][3]);
                float w = fmaxf(rx - lx, 0.f);
                float h = fmaxf(ry - ly, 0.f);
                float inter = w * h;
                float uni = aarea + area[j] - inter;
                float iou = inter / fmaxf(uni, 1e-10f);
                if (iou > MAX_OVERLAP) sup[j] = 1;
            }
        }
        __syncthreads();                      // all suppression writes done
        if (active && tid == 0) sup[i] = 0;   // un-suppress self
    }
    __syncthreads();

    // write per-class candidates
    float* osc = cand_sc + ((size_t)(b*NC + c))*WPRE;
    float* obx = cand_bx + ((size_t)(b*NC + c))*WPRE*4;
    for (int i = tid; i < WPRE; i += 256) {
        bool keep = validf[i] && !sup[i];
        osc[i] = keep ? vals[i] : -1.0f;
        obx[i*4+0] = cbox[i][0]; obx[i*4+1] = cbox[i][1];
        obx[i*4+2] = cbox[i][2]; obx[i*4+3] = cbox[i][3];
    }
}

// ---------------- Kernel 3: final per-image top-K ----------------
__global__ __launch_bounds__(256) void topk_kernel(
    const float* __restrict__ cand_sc, const float* __restrict__ cand_bx,
    float* __restrict__ out, int NC, int TOPK, int B)
{
    const int b = blockIdx.x;
    const int tid = threadIdx.x;
    const int N = NC * WPRE;
    const float* s = cand_sc + (size_t)b * N;

    __shared__ u32 hist[256];
    __shared__ u64 cand[256];
    __shared__ u64 sh_prefix;
    __shared__ int sh_r, sh_cnt;

    if (tid == 0) { sh_prefix = 0ull; sh_r = TOPK; sh_cnt = 0; }
    __syncthreads();

    for (int d = 7; d >= 0; --d) {
        hist[tid] = 0;
        __syncthreads();
        u64 pref = sh_prefix;
        for (int i = tid; i < N; i += 256) {
            u64 k = score_key(s[i], i);
            bool match = (d == 7) || ((k >> ((d+1)*8)) == pref);
            if (match) atomicAdd(&hist[(u32)(k >> (d*8)) & 255u], 1u);
        }
        __syncthreads();
        if (tid == 0) {
            u32 r = (u32)sh_r, cum = 0; int sel = 0;
            for (int v = 255; v >= 0; --v) {
                u32 h = hist[v];
                if (cum + h >= r) { sel = v; sh_r = (int)(r - cum); break; }
                cum += h;
            }
            sh_prefix = (pref << 8) | (u64)(u32)sel;
        }
        __syncthreads();
    }
    u64 pivot = sh_prefix;

    for (int i = tid; i < N; i += 256) {
        u64 k = score_key(s[i], i);
        if (k >= pivot) {
            int pos = atomicAdd(&sh_cnt, 1);
            if (pos < 256) cand[pos] = k;
        }
    }
    if (tid >= TOPK) cand[tid] = 0ull;
    __syncthreads();

    // bitonic sort 256 descending
    for (int k = 2; k <= 256; k <<= 1) {
        for (int j = k >> 1; j > 0; j >>= 1) {
            int ixj = tid ^ j;
            if (ixj > tid) {
                u64 a = cand[tid], bb = cand[ixj];
                if (((tid & k) == 0) ? (a < bb) : (a > bb)) {
                    cand[tid] = bb; cand[ixj] = a;
                }
            }
            __syncthreads();
        }
    }

    if (tid < TOPK) {
        u64 k = cand[tid];
        float sc = key_score(k);
        int flat = key_idx(k);
        int cls = flat / WPRE;
        const float* bx = cand_bx + ((size_t)b*N + flat)*4;
        float* ob = out + ((size_t)(b*TOPK + tid))*4;
        ob[0] = bx[0]; ob[1] = bx[1]; ob[2] = bx[2]; ob[3] = bx[3];
        out[(size_t)B*TOPK*4 + (size_t)b*TOPK + tid] = (float)(cls + 1);  // labels as f32
        out[(size_t)B*TOPK*5 + (size_t)b*TOPK + tid] = sc;
    }
}

extern "C" void kernel_launch(void* const* d_in, const int* in_sizes, int n_in,
                              void* d_out, int out_size, void* d_ws, size_t ws_size,
                              hipStream_t stream) {
    const float* locs   = (const float*)d_in[0];
    const float* scores = (const float*)d_in[1];
    const float* priors = (const float*)d_in[2];

    const int P  = in_sizes[2] / 4;          // 8732
    const int B  = in_sizes[0] / (4 * P);    // 8
    const int C  = in_sizes[1] / (B * P);    // 81
    const int NC = C - 1;                    // 80
    const int TOPK = out_size / (B * 6);     // 200  (4 box + 1 label + 1 score)

    float* ws      = (float*)d_ws;
    float* dec     = ws;                                    // B*P*4
    float* probs_t = dec + (size_t)B * P * 4;               // B*NC*P
    float* cand_sc = probs_t + (size_t)B * NC * P;          // B*NC*WPRE
    float* cand_bx = cand_sc + (size_t)B * NC * WPRE;       // B*NC*WPRE*4

    dim3 g1((P + 255) / 256, B);
    decode_softmax_kernel<<<g1, 256, 0, stream>>>(locs, scores, priors, dec, probs_t, P, C, NC);

    dim3 g2(NC, B);
    nms_kernel<<<g2, 256, 0, stream>>>(dec, probs_t, cand_sc, cand_bx, P, NC);

    topk_kernel<<<dim3(B), 256, 0, stream>>>(cand_sc, cand_bx, (float*)d_out, NC, TOPK, B);
}

// Round 2
// 269.863 us; speedup vs baseline: 2.5443x; 2.5443x over previous
//
#include <hip/hip_runtime.h>
#include <cstdint>

typedef unsigned long long u64;
typedef unsigned int u32;

#define WPRE 400
#define MIN_SCORE 0.01f
#define MAX_OVERLAP 0.45f

__device__ __forceinline__ u32 f32_key(float f) {
    u32 u = __float_as_uint(f);
    return (f >= 0.0f) ? (u | 0x80000000u) : ~u;
}
__device__ __forceinline__ float key_f32(u32 k) {
    return __uint_as_float((k & 0x80000000u) ? (k ^ 0x80000000u) : ~k);
}

// Exact K-th selection over 32-bit keys (descending), 4 x 8-bit MSD radix.
// pivot  = K-th largest key among participants
// needed = how many elements equal to pivot belong in the top-K
// nge    = # participants with key >= pivot  ( = n_gt + n_eq )
template <typename KF>
__device__ void radix_select32(KF kf, int N, int K, int tid, int T,
                               u32* hist, u32* sh_prefix, int* sh_r, int* sh_neq,
                               u32& pivot, int& needed, int& nge)
{
    if (tid == 0) { *sh_prefix = 0u; *sh_r = K; *sh_neq = 0; }
    __syncthreads();
    for (int d = 3; d >= 0; --d) {
        u32 pref = *sh_prefix;
        int r = *sh_r;
        if (tid < 256) hist[tid] = 0u;
        __syncthreads();
        for (int i = tid; i < N; i += T) {
            u32 k;
            if (!kf(i, k)) continue;
            bool match = (d == 3) || (((k ^ pref) >> ((d + 1) * 8)) == 0u);
            if (match) atomicAdd(&hist[(k >> (d * 8)) & 255u], 1u);
        }
        __syncthreads();
        // parallel inclusive suffix sum over 256 bins
        for (int off = 1; off < 256; off <<= 1) {
            u32 v = 0u;
            if (tid < 256) v = hist[tid] + ((tid + off < 256) ? hist[tid + off] : 0u);
            __syncthreads();
            if (tid < 256) hist[tid] = v;
            __syncthreads();
        }
        if (tid < 256) {
            u32 Sv = hist[tid];
            u32 Sn = (tid < 255) ? hist[tid + 1] : 0u;
            if ((int)Sv >= r && (int)Sn < r) {
                *sh_prefix = pref | ((u32)tid << (d * 8));
                *sh_r = r - (int)Sn;
                *sh_neq = (int)(Sv - Sn);
            }
        }
        __syncthreads();
    }
    u32 pv = *sh_prefix; int nd = *sh_r; int ne = *sh_neq;
    __syncthreads();   // everyone has read before state is reused
    pivot = pv; needed = nd; nge = (K - nd) + ne;
}

// ---------------- Kernel 1: decode boxes + softmax (LDS-staged, coalesced) ----------------
__global__ __launch_bounds__(256) void decode_softmax_kernel(
    const float* __restrict__ locs, const float* __restrict__ scores,
    const float* __restrict__ priors, float* __restrict__ dec,
    float* __restrict__ probs_t, int P, int C, int NC)
{
    __shared__ float tile[64 * 81];
    __shared__ float mrow[64], srow[64];
    const int b  = blockIdx.y;
    const int p0 = blockIdx.x * 64;
    const int tid = threadIdx.x;
    const int nrows = min(64, P - p0);
    const int n = nrows * C;

    // contiguous coalesced stage of scores[b, p0:p0+64, :]
    const float* src = scores + ((size_t)b * P + p0) * C;
    for (int idx = tid; idx < n; idx += 256) tile[idx] = src[idx];

    // decode boxes (same float expressions as round-1, bit-exact)
    if (tid < nrows) {
        int p = p0 + tid;
        float4 lc = ((const float4*)locs)[(size_t)b * P + p];
        float4 pr = ((const float4*)priors)[p];
        float cx = lc.x * pr.z / 10.0f + pr.x;
        float cy = lc.y * pr.w / 10.0f + pr.y;
        float w  = expf(lc.z / 5.0f) * pr.z;
        float h  = expf(lc.w / 5.0f) * pr.w;
        ((float4*)dec)[(size_t)b * P + p] =
            make_float4(cx - w * 0.5f, cy - h * 0.5f, cx + w * 0.5f, cy + h * 0.5f);
    }
    __syncthreads();

    // per-row sequential max & sum (same accumulation order as round-1)
    if (tid < nrows) {
        const float* row = &tile[tid * C];
        float m = row[0];
        for (int cc = 1; cc < C; ++cc) m = fmaxf(m, row[cc]);
        float ss = 0.f;
        for (int cc = 0; cc < C; ++cc) ss += expf(row[cc] - m);
        mrow[tid] = m; srow[tid] = ss;
    }
    __syncthreads();

    // transposed, coalesced write of probs (skip background class 0)
    for (int idx = tid; idx < 64 * NC; idx += 256) {
        int r  = idx & 63;
        int cc = idx >> 6;
        if (r < nrows) {
            float v = expf(tile[r * C + cc + 1] - mrow[r]) / srow[r];
            probs_t[((size_t)(b * NC + cc)) * P + p0 + r] = v;
        }
    }
}

// ---------------- Kernel 2: per (class,image) top-400 + NMS ----------------
__global__ __launch_bounds__(512) void nms_kernel(
    const float* __restrict__ dec, const float* __restrict__ probs_t,
    float* __restrict__ cand_sc, float* __restrict__ cand_bx,
    int P, int NC)
{
    const int c = blockIdx.x, b = blockIdx.y;
    const int tid = threadIdx.x;
    const int T = 512;

    __shared__ u32 skey[8736];
    __shared__ u32 hist[256];
    __shared__ u64 cand[512];
    __shared__ float x0a[448], y0a[448], x1a[448], y1a[448], ara[448];
    __shared__ float vals[WPRE];
    __shared__ u64 rowm[WPRE * 8];
    __shared__ u64 validm[7], keepm[7];
    __shared__ u32 sh_prefix;
    __shared__ int sh_r, sh_neq, sh_cnt;

    const float* ps = probs_t + ((size_t)(b * NC + c)) * P;

    // stage masked sortable keys to LDS (one global pass)
    for (int i = tid; i < P; i += T) {
        float f = ps[i];
        f = (f > MIN_SCORE) ? f : -1.0f;
        skey[i] = f32_key(f);
    }
    if (tid == 0) sh_cnt = 0;
    __syncthreads();

    u32 pivot; int needed, nge;
    radix_select32([&](int i, u32& k) { k = skey[i]; return true; },
                   P, WPRE, tid, T, hist, &sh_prefix, &sh_r, &sh_neq,
                   pivot, needed, nge);

    if (nge <= 512) {
        for (int i = tid; i < P; i += T) {
            u32 k = skey[i];
            if (k >= pivot) {
                int pos = atomicAdd(&sh_cnt, 1);
                cand[pos] = ((u64)k << 32) | (u64)(~(u32)i);
            }
        }
    } else {
        // tie flood at pivot (e.g. <400 valid -> -1.0 mass): exact secondary
        // select on index key (~i, larger = smaller index) among equals.
        u32 pivot2; int needed2, nge2;
        radix_select32([&](int i, u32& k) {
                           if (skey[i] != pivot) return false;
                           k = ~(u32)i; return true;
                       },
                       P, needed, tid, T, hist, &sh_prefix, &sh_r, &sh_neq,
                       pivot2, needed2, nge2);
        for (int i = tid; i < P; i += T) {
            u32 k = skey[i];
            if (k > pivot || (k == pivot && (~(u32)i) >= pivot2)) {
                int pos = atomicAdd(&sh_cnt, 1);
                cand[pos] = ((u64)k << 32) | (u64)(~(u32)i);
            }
        }
    }
    __syncthreads();
    int cnt = sh_cnt;
    if (tid >= cnt) cand[tid] = 0ull;   // pad to 512
    __syncthreads();

    // bitonic sort 512 desc: (score desc, index asc)
    for (int k = 2; k <= 512; k <<= 1) {
        for (int j = k >> 1; j > 0; j >>= 1) {
            int ixj = tid ^ j;
            if (ixj > tid) {
                u64 a = cand[tid], bb = cand[ixj];
                if (((tid & k) == 0) ? (a < bb) : (a > bb)) {
                    cand[tid] = bb; cand[ixj] = a;
                }
            }
            __syncthreads();
        }
    }

    // unpack top-400 into SoA (padded to 448 with zeros)
    for (int i = tid; i < 448; i += T) {
        if (i < WPRE) {
            u64 kk = cand[i];
            vals[i] = key_f32((u32)(kk >> 32));
            int p = (int)(~(u32)kk);
            float4 bx = ((const float4*)dec)[(size_t)b * P + p];
            x0a[i] = bx.x; y0a[i] = bx.y; x1a[i] = bx.z; y1a[i] = bx.w;
            ara[i] = (bx.z - bx.x) * (bx.w - bx.y);
        } else {
            x0a[i] = 0.f; y0a[i] = 0.f; x1a[i] = 0.f; y1a[i] = 0.f; ara[i] = 0.f;
        }
    }
    __syncthreads();

    // valid bitmask via wave ballot (waves 0..6 fully cover 448 slots)
    if (tid < 448) {
        bool pred = (tid < WPRE) && (vals[tid] > MIN_SCORE);
        u64 mk = __ballot(pred);
        if ((tid & 63) == 0) validm[tid >> 6] = mk;
    }
    __syncthreads();

    // suppression bit-matrix: cell = w*400 + i  (lanes: consecutive i, same w
    // -> box_i reads stride-1, box_j reads broadcast). Exact IEEE division.
    for (int cell = tid; cell < WPRE * 7; cell += T) {
        int i = cell % WPRE;
        int w = cell / WPRE;
        float xi0 = x0a[i], yi0 = y0a[i], xi1 = x1a[i], yi1 = y1a[i], ai = ara[i];
        u64 m = 0ull;
        int jb = w << 6;
        int nt = (w == 6) ? (WPRE - 384) : 64;
        for (int t = 0; t < nt; ++t) {
            int j = jb + t;
            float lx = fmaxf(xi0, x0a[j]);
            float ly = fmaxf(yi0, y0a[j]);
            float rx = fminf(xi1, x1a[j]);
            float ry = fminf(yi1, y1a[j]);
            float ww = fmaxf(rx - lx, 0.f);
            float hh = fmaxf(ry - ly, 0.f);
            float inter = ww * hh;
            float uni = ai + ara[j] - inter;
            float iou = inter / fmaxf(uni, 1e-10f);
            if (iou > MAX_OVERLAP) m |= (1ull << t);
        }
        if ((i >> 6) == w) m &= ~(1ull << (i & 63));  // pre-clear diagonal
        rowm[i * 8 + w] = m;
    }
    __syncthreads();

    // serial scan in ONE wave, zero barriers (ballot broadcast of the active bit)
    if (tid < 64) {
        u64 supw = 0ull;
        u64 valw = (tid < 7) ? validm[tid] : 0ull;
        for (int i = 0; i < WPRE; ++i) {
            u64 row = (tid < 7) ? rowm[i * 8 + tid] : 0ull;  // prefetch, indep of supw
            u64 avail = valw & ~supw;
            bool mybit = (tid == (i >> 6)) && ((avail >> (i & 63)) & 1ull);
            u64 vote = __ballot(mybit);
            if (vote) supw |= row;
        }
        if (tid < 7) keepm[tid] = valw & ~supw;
    }
    __syncthreads();

    // write per-class candidates
    float* osc = cand_sc + ((size_t)(b * NC + c)) * WPRE;
    float4* obx = (float4*)cand_bx + ((size_t)(b * NC + c)) * WPRE;
    for (int i = tid; i < WPRE; i += T) {
        bool keep = (keepm[i >> 6] >> (i & 63)) & 1ull;
        osc[i] = keep ? vals[i] : -1.0f;
        obx[i] = make_float4(x0a[i], y0a[i], x1a[i], y1a[i]);
    }
}

// ---------------- Kernel 3: final per-image top-K ----------------
__global__ __launch_bounds__(1024) void topk_kernel(
    const float* __restrict__ cand_sc, const float* __restrict__ cand_bx,
    float* __restrict__ out, int NC, int TOPK, int B)
{
    const int b = blockIdx.x;
    const int tid = threadIdx.x;
    const int T = 1024;
    const int N = NC * WPRE;   // 32000

    __shared__ u32 skey[32000];
    __shared__ u32 hist[256];
    __shared__ u64 cand[256];
    __shared__ u32 sh_prefix;
    __shared__ int sh_r, sh_neq, sh_cnt;

    const float* s = cand_sc + (size_t)b * N;
    for (int i = tid; i < N; i += T) skey[i] = f32_key(s[i]);
    if (tid == 0) sh_cnt = 0;
    __syncthreads();

    u32 pivot; int needed, nge;
    radix_select32([&](int i, u32& k) { k = skey[i]; return true; },
                   N, TOPK, tid, T, hist, &sh_prefix, &sh_r, &sh_neq,
                   pivot, needed, nge);

    if (nge <= 256) {
        for (int i = tid; i < N; i += T) {
            u32 k = skey[i];
            if (k >= pivot) {
                int pos = atomicAdd(&sh_cnt, 1);
                cand[pos] = ((u64)k << 32) | (u64)(~(u32)i);
            }
        }
    } else {
        u32 pivot2; int needed2, nge2;
        radix_select32([&](int i, u32& k) {
                           if (skey[i] != pivot) return false;
                           k = ~(u32)i; return true;
                       },
                       N, needed, tid, T, hist, &sh_prefix, &sh_r, &sh_neq,
                       pivot2, needed2, nge2);
        for (int i = tid; i < N; i += T) {
            u32 k = skey[i];
            if (k > pivot || (k == pivot && (~(u32)i) >= pivot2)) {
                int pos = atomicAdd(&sh_cnt, 1);
                cand[pos] = ((u64)k << 32) | (u64)(~(u32)i);
            }
        }
    }
    __syncthreads();
    int cnt = sh_cnt;
    if (tid < 256 && tid >= cnt) cand[tid] = 0ull;
    __syncthreads();

    // bitonic sort 256 desc
    for (int k = 2; k <= 256; k <<= 1) {
        for (int j = k >> 1; j > 0; j >>= 1) {
            if (tid < 256) {
                int ixj = tid ^ j;
                if (ixj > tid) {
                    u64 a = cand[tid], bb = cand[ixj];
                    if (((tid & k) == 0) ? (a < bb) : (a > bb)) {
                        cand[tid] = bb; cand[ixj] = a;
                    }
                }
            }
            __syncthreads();
        }
    }

    if (tid < TOPK) {
        u64 kk = cand[tid];
        float sc = key_f32((u32)(kk >> 32));
        int flat = (int)(~(u32)kk);
        int cls = flat / WPRE;
        float4 bx = ((const float4*)cand_bx)[(size_t)b * N + flat];
        float* ob = out + ((size_t)(b * TOPK + tid)) * 4;
        ob[0] = bx.x; ob[1] = bx.y; ob[2] = bx.z; ob[3] = bx.w;
        out[(size_t)B * TOPK * 4 + (size_t)b * TOPK + tid] = (float)(cls + 1);
        out[(size_t)B * TOPK * 5 + (size_t)b * TOPK + tid] = sc;
    }
}

extern "C" void kernel_launch(void* const* d_in, const int* in_sizes, int n_in,
                              void* d_out, int out_size, void* d_ws, size_t ws_size,
                              hipStream_t stream) {
    const float* locs   = (const float*)d_in[0];
    const float* scores = (const float*)d_in[1];
    const float* priors = (const float*)d_in[2];

    const int P  = in_sizes[2] / 4;          // 8732
    const int B  = in_sizes[0] / (4 * P);    // 8
    const int C  = in_sizes[1] / (B * P);    // 81
    const int NC = C - 1;                    // 80
    const int TOPK = out_size / (B * 6);     // 200

    float* ws      = (float*)d_ws;
    float* dec     = ws;                                    // B*P*4
    float* probs_t = dec + (size_t)B * P * 4;               // B*NC*P
    float* cand_sc = probs_t + (size_t)B * NC * P;          // B*NC*WPRE
    float* cand_bx = cand_sc + (size_t)B * NC * WPRE;       // B*NC*WPRE*4

    dim3 g1((P + 63) / 64, B);
    decode_softmax_kernel<<<g1, 256, 0, stream>>>(locs, scores, priors, dec, probs_t, P, C, NC);

    dim3 g2(NC, B);
    nms_kernel<<<g2, 512, 0, stream>>>(dec, probs_t, cand_sc, cand_bx, P, NC);

    topk_kernel<<<dim3(B), 1024, 0, stream>>>(cand_sc, cand_bx, (float*)d_out, NC, TOPK, B);
}